// Round 1
// baseline (2348.422 us; speedup 1.0000x reference)
//
#include <hip/hip_runtime.h>

#define HC 128
#define EPS_BN 1e-5f

// ---------------- degree / normalization ----------------
__global__ void deg_kernel(const int* __restrict__ dst, float* __restrict__ deg, int E) {
    int e = blockIdx.x * 256 + threadIdx.x;
    if (e < E) atomicAdd(&deg[dst[e]], 1.0f);
}

__global__ void dis_kernel(float* __restrict__ deg, int n) {
    int i = blockIdx.x * 256 + threadIdx.x;
    if (i < n) deg[i] = rsqrtf(deg[i] + 1.0f);   // +1 for self-loop; deg>=1 guaranteed
}

// ---------------- fp32 GEMM: Y[n,128] = X[n,128] @ W[128,128] ----------------
__global__ __launch_bounds__(256) void gemm128(const float* __restrict__ X,
                                               const float* __restrict__ W,
                                               float* __restrict__ Y, int n) {
    __shared__ float xs[64][HC];
    const int tid  = threadIdx.x;
    const int row0 = blockIdx.x * 64;

    // cooperative load of 64x128 X tile (float4, coalesced)
    const float4* Xv  = (const float4*)(X + (size_t)row0 * HC);
    float4*       xsv = (float4*)&xs[0][0];
    for (int i = tid; i < 64 * HC / 4; i += 256) {
        int r = i >> 5;                    // 32 float4 per row
        float4 v = make_float4(0.f, 0.f, 0.f, 0.f);
        if (row0 + r < n) v = Xv[i];
        xsv[i] = v;
    }
    __syncthreads();

    const int c  = tid & 127;
    const int rh = tid >> 7;
    for (int r = rh; r < 64; r += 2) {
        if (row0 + r >= n) break;
        float acc = 0.f;
#pragma unroll 8
        for (int k = 0; k < HC; ++k)
            acc = fmaf(xs[r][k], W[k * HC + c], acc);
        Y[(size_t)(row0 + r) * HC + c] = acc;
    }
}

// ---------------- aggregation: self-loop init + bias ----------------
__global__ void selfloop_init(const float* __restrict__ xw, const float* __restrict__ dis,
                              const float* __restrict__ b, float* __restrict__ agg, int n) {
    int i = blockIdx.x * 256 + threadIdx.x;
    if (i < n * HC) {
        int node = i >> 7, c = i & 127;
        float d = dis[node];
        agg[i] = xw[i] * d * d + b[c];
    }
}

// ---------------- aggregation: per-edge atomic scatter ----------------
__global__ __launch_bounds__(256) void scatter_kernel(const float* __restrict__ xw,
                                                      const int* __restrict__ src,
                                                      const int* __restrict__ dst,
                                                      const float* __restrict__ dis,
                                                      float* __restrict__ agg, int E) {
    int e = blockIdx.x * 2 + (threadIdx.x >> 7);
    int c = threadIdx.x & 127;
    if (e < E) {
        int s = src[e], d = dst[e];
        float norm = dis[s] * dis[d];
        atomicAdd(&agg[(size_t)d * HC + c], xw[(size_t)s * HC + c] * norm);
    }
}

// ---------------- BatchNorm stats (per-channel sum / sumsq) ----------------
__global__ __launch_bounds__(256) void bn_stats(const float* __restrict__ x,
                                                float* __restrict__ sums,
                                                float* __restrict__ sumsq, int n) {
    __shared__ float ss[256], sq[256];
    const int tid = threadIdx.x;
    const int c = tid & 127, half = tid >> 7;
    float s = 0.f, q = 0.f;
    for (int r = blockIdx.x * 2 + half; r < n; r += gridDim.x * 2) {
        float v = x[(size_t)r * HC + c];
        s += v; q += v * v;
    }
    ss[tid] = s; sq[tid] = q;
    __syncthreads();
    if (half == 0) {
        atomicAdd(&sums[c],  ss[tid] + ss[tid + 128]);
        atomicAdd(&sumsq[c], sq[tid] + sq[tid + 128]);
    }
}

__global__ void bn_finalize(const float* __restrict__ sums, const float* __restrict__ sumsq,
                            const float* __restrict__ g, const float* __restrict__ be,
                            float* __restrict__ scale, float* __restrict__ shift, int n) {
    int c = threadIdx.x;
    float m = sums[c] / (float)n;
    float v = sumsq[c] / (float)n - m * m;
    float sc = g[c] * rsqrtf(fmaxf(v, 0.f) + EPS_BN);
    scale[c] = sc;
    shift[c] = be[c] - m * sc;
}

__global__ void bn_apply_relu(float* __restrict__ x, const float* __restrict__ scale,
                              const float* __restrict__ shift, int n) {
    int i = blockIdx.x * 256 + threadIdx.x;
    if (i < n * HC) {
        int c = i & 127;
        x[i] = fmaxf(fmaf(x[i], scale[c], shift[c]), 0.f);
    }
}

// ---------------- fused MLP head: relu(h@Wm1+bm1)@Wm2+bm2 ----------------
__global__ __launch_bounds__(256) void mlp_kernel(const float* __restrict__ h,
                                                  const float* __restrict__ Wm1,
                                                  const float* __restrict__ bm1,
                                                  const float* __restrict__ Wm2,
                                                  const float* __restrict__ bm2,
                                                  float* __restrict__ out, int n) {
    const int lane = threadIdx.x & 63;
    const int node = blockIdx.x * 4 + (threadIdx.x >> 6);
    if (node >= n) return;
    const float* hr = h + (size_t)node * HC;
    float acc = bm1[lane];
#pragma unroll 8
    for (int k = 0; k < HC; ++k)
        acc = fmaf(hr[k], Wm1[k * 64 + lane], acc);
    acc = fmaxf(acc, 0.f);
    float o = acc * Wm2[lane];
#pragma unroll
    for (int off = 32; off; off >>= 1)
        o += __shfl_down(o, off);
    if (lane == 0) out[node] = o + bm2[0];
}

extern "C" void kernel_launch(void* const* d_in, const int* in_sizes, int n_in,
                              void* d_out, int out_size, void* d_ws, size_t ws_size,
                              hipStream_t stream) {
    const float* x   = (const float*)d_in[0];
    const int*   ei  = (const int*)  d_in[1];
    const float* W1  = (const float*)d_in[2];
    const float* b1  = (const float*)d_in[3];
    const float* g1  = (const float*)d_in[4];
    const float* be1 = (const float*)d_in[5];
    const float* W2  = (const float*)d_in[6];
    const float* b2  = (const float*)d_in[7];
    const float* g2  = (const float*)d_in[8];
    const float* be2 = (const float*)d_in[9];
    const float* Wm1 = (const float*)d_in[10];
    const float* bm1 = (const float*)d_in[11];
    const float* Wm2 = (const float*)d_in[12];
    const float* bm2 = (const float*)d_in[13];
    float* out = (float*)d_out;

    const int n = in_sizes[0] / HC;       // 100000
    const int E = in_sizes[1] / 2;        // 1600000
    const int* srcp = ei;
    const int* dstp = ei + E;

    char* ws = (char*)d_ws;
    size_t off = 0;
    float* dis  = (float*)(ws + off); off += ((size_t)n * 4 + 511) & ~511ULL;
    float* bufA = (float*)(ws + off); off += (size_t)n * HC * 4;
    float* bufB = (float*)(ws + off); off += (size_t)n * HC * 4;
    float* sums = (float*)(ws + off); off += 512;   // sums[128] | sumsq[128] contiguous
    float* sumsq = sums + 128;
    float* scale = (float*)(ws + off); off += 512;
    float* shift = scale + 128;

    const int elemBlocks = (n * HC + 255) / 256;

    // normalization coefficients
    hipMemsetAsync(dis, 0, (size_t)n * 4, stream);
    deg_kernel<<<(E + 255) / 256, 256, 0, stream>>>(dstp, dis, E);
    dis_kernel<<<(n + 255) / 256, 256, 0, stream>>>(dis, n);

    // ---- layer 1 ----
    gemm128<<<(n + 63) / 64, 256, 0, stream>>>(x, W1, bufA, n);
    selfloop_init<<<elemBlocks, 256, 0, stream>>>(bufA, dis, b1, bufB, n);
    scatter_kernel<<<(E + 1) / 2, 256, 0, stream>>>(bufA, srcp, dstp, dis, bufB, E);
    hipMemsetAsync(sums, 0, 1024, stream);
    bn_stats<<<512, 256, 0, stream>>>(bufB, sums, sumsq, n);
    bn_finalize<<<1, 128, 0, stream>>>(sums, sumsq, g1, be1, scale, shift, n);
    bn_apply_relu<<<elemBlocks, 256, 0, stream>>>(bufB, scale, shift, n);

    // ---- layer 2 ----
    gemm128<<<(n + 63) / 64, 256, 0, stream>>>(bufB, W2, bufA, n);
    selfloop_init<<<elemBlocks, 256, 0, stream>>>(bufA, dis, b2, bufB, n);
    scatter_kernel<<<(E + 1) / 2, 256, 0, stream>>>(bufA, srcp, dstp, dis, bufB, E);
    hipMemsetAsync(sums, 0, 1024, stream);
    bn_stats<<<512, 256, 0, stream>>>(bufB, sums, sumsq, n);
    bn_finalize<<<1, 128, 0, stream>>>(sums, sumsq, g2, be2, scale, shift, n);
    bn_apply_relu<<<elemBlocks, 256, 0, stream>>>(bufB, scale, shift, n);

    // ---- MLP head ----
    mlp_kernel<<<(n + 3) / 4, 256, 0, stream>>>(bufB, Wm1, bm1, Wm2, bm2, out, n);
}

// Round 2
// 1347.886 us; speedup vs baseline: 1.7423x; 1.7423x over previous
//
#include <hip/hip_runtime.h>

#define HC 128
#define EPS_BN 1e-5f

// ---------------- degree count (int) ----------------
__global__ void degi_kernel(const int* __restrict__ dst, int* __restrict__ degi, int E) {
    int e = blockIdx.x * 256 + threadIdx.x;
    if (e < E) atomicAdd(&degi[dst[e]], 1);
}

__global__ void dis_kernel(const int* __restrict__ degi, float* __restrict__ dis, int n) {
    int i = blockIdx.x * 256 + threadIdx.x;
    if (i < n) dis[i] = rsqrtf((float)degi[i] + 1.0f);  // +1 self-loop
}

// ---------------- exclusive scan of degi -> rowptr (3 passes) ----------------
// pass1: per-block (1024 elems) exclusive scan into `excl`, block totals into bsums
__global__ __launch_bounds__(256) void scan1(const int* __restrict__ degi, int* __restrict__ excl,
                                             int* __restrict__ bsums, int n) {
    __shared__ int ts[256];
    const int tid = threadIdx.x;
    const int base = blockIdx.x * 1024 + tid * 4;
    int v0 = 0, v1 = 0, v2 = 0, v3 = 0;
    if (base + 3 < n) {
        int4 v = *(const int4*)(degi + base);
        v0 = v.x; v1 = v.y; v2 = v.z; v3 = v.w;
    } else {
        if (base + 0 < n) v0 = degi[base + 0];
        if (base + 1 < n) v1 = degi[base + 1];
        if (base + 2 < n) v2 = degi[base + 2];
        if (base + 3 < n) v3 = degi[base + 3];
    }
    int p1 = v0, p2 = v0 + v1, p3 = v0 + v1 + v2, total = p3 + v3;
    ts[tid] = total;
    __syncthreads();
    for (int off = 1; off < 256; off <<= 1) {
        int t = (tid >= off) ? ts[tid - off] : 0;
        __syncthreads();
        ts[tid] += t;
        __syncthreads();
    }
    int eb = (tid ? ts[tid - 1] : 0);
    if (tid == 255) bsums[blockIdx.x] = ts[255];
    if (base + 0 < n) excl[base + 0] = eb;
    if (base + 1 < n) excl[base + 1] = eb + p1;
    if (base + 2 < n) excl[base + 2] = eb + p2;
    if (base + 3 < n) excl[base + 3] = eb + p3;
}

// pass2: serial exclusive scan of block sums (~98 entries)
__global__ void scan2(int* __restrict__ bsums, int nb) {
    if (threadIdx.x == 0) {
        int s = 0;
        for (int i = 0; i < nb; ++i) { int t = bsums[i]; bsums[i] = s; s += t; }
    }
}

// pass3: add block offsets; excl (==cursor buffer) updated in place, rowptr written
__global__ void scan3(int* __restrict__ cursor, const int* __restrict__ bsums,
                      int* __restrict__ rowptr, int n, int E) {
    int i = blockIdx.x * 256 + threadIdx.x;
    if (i < n) {
        int v = cursor[i] + bsums[i >> 10];
        rowptr[i] = v;
        cursor[i] = v;
    }
    if (i == n) rowptr[n] = E;
}

// ---------------- edge placement into CSR, with precomputed coef ----------------
__global__ void edge_place(const int* __restrict__ src, const int* __restrict__ dst,
                           const float* __restrict__ dis, int* __restrict__ cursor,
                           int* __restrict__ srcs, float* __restrict__ coef, int E) {
    int e = blockIdx.x * 256 + threadIdx.x;
    if (e < E) {
        int s = src[e], d = dst[e];
        int pos = atomicAdd(&cursor[d], 1);
        srcs[pos] = s;
        coef[pos] = dis[s] * dis[d];
    }
}

// ---------------- fp32 GEMM: Y[n,128] = X[n,128] @ W[128,128] ----------------
__global__ __launch_bounds__(256) void gemm128(const float* __restrict__ X,
                                               const float* __restrict__ W,
                                               float* __restrict__ Y, int n) {
    __shared__ float xs[64][HC];
    const int tid  = threadIdx.x;
    const int row0 = blockIdx.x * 64;

    const float4* Xv  = (const float4*)(X + (size_t)row0 * HC);
    float4*       xsv = (float4*)&xs[0][0];
    for (int i = tid; i < 64 * HC / 4; i += 256) {
        int r = i >> 5;
        float4 v = make_float4(0.f, 0.f, 0.f, 0.f);
        if (row0 + r < n) v = Xv[i];
        xsv[i] = v;
    }
    __syncthreads();

    const int c  = tid & 127;
    const int rh = tid >> 7;
    for (int r = rh; r < 64; r += 2) {
        if (row0 + r >= n) break;
        float acc = 0.f;
#pragma unroll 8
        for (int k = 0; k < HC; ++k)
            acc = fmaf(xs[r][k], W[k * HC + c], acc);
        Y[(size_t)(row0 + r) * HC + c] = acc;
    }
}

// ---------------- CSR gather aggregation (self-loop + bias fused) ----------------
// one wave per node; lane handles 2 channels (float2)
__global__ __launch_bounds__(256) void gcn_agg(const float* __restrict__ xw,
                                               const int* __restrict__ srcs,
                                               const float* __restrict__ coef,
                                               const int* __restrict__ rowptr,
                                               const float* __restrict__ dis,
                                               const float* __restrict__ b,
                                               float* __restrict__ out, int n) {
    const int node = blockIdx.x * 4 + (threadIdx.x >> 6);
    const int lane = threadIdx.x & 63;
    if (node >= n) return;
    const float2* xw2 = (const float2*)xw;
    float d = dis[node];
    float2 acc = xw2[(size_t)node * 64 + lane];
    float2 bb  = ((const float2*)b)[lane];
    acc.x = fmaf(acc.x, d * d, bb.x);
    acc.y = fmaf(acc.y, d * d, bb.y);
    const int e1 = rowptr[node + 1];
    for (int e = rowptr[node]; e < e1; ++e) {
        int s = srcs[e];
        float c = coef[e];
        float2 v = xw2[(size_t)s * 64 + lane];
        acc.x = fmaf(v.x, c, acc.x);
        acc.y = fmaf(v.y, c, acc.y);
    }
    ((float2*)out)[(size_t)node * 64 + lane] = acc;
}

// ---------------- BatchNorm ----------------
__global__ __launch_bounds__(256) void bn_stats(const float* __restrict__ x,
                                                float* __restrict__ sums,
                                                float* __restrict__ sumsq, int n) {
    __shared__ float ss[256], sq[256];
    const int tid = threadIdx.x;
    const int c = tid & 127, half = tid >> 7;
    float s = 0.f, q = 0.f;
    for (int r = blockIdx.x * 2 + half; r < n; r += gridDim.x * 2) {
        float v = x[(size_t)r * HC + c];
        s += v; q += v * v;
    }
    ss[tid] = s; sq[tid] = q;
    __syncthreads();
    if (half == 0) {
        atomicAdd(&sums[c],  ss[tid] + ss[tid + 128]);
        atomicAdd(&sumsq[c], sq[tid] + sq[tid + 128]);
    }
}

__global__ void bn_finalize(const float* __restrict__ sums, const float* __restrict__ sumsq,
                            const float* __restrict__ g, const float* __restrict__ be,
                            float* __restrict__ scale, float* __restrict__ shift, int n) {
    int c = threadIdx.x;
    float m = sums[c] / (float)n;
    float v = sumsq[c] / (float)n - m * m;
    float sc = g[c] * rsqrtf(fmaxf(v, 0.f) + EPS_BN);
    scale[c] = sc;
    shift[c] = be[c] - m * sc;
}

__global__ void bn_apply_relu(float* __restrict__ x, const float* __restrict__ scale,
                              const float* __restrict__ shift, int n) {
    int i = blockIdx.x * 256 + threadIdx.x;
    if (i < n * HC) {
        int c = i & 127;
        x[i] = fmaxf(fmaf(x[i], scale[c], shift[c]), 0.f);
    }
}

// ---------------- fused MLP head ----------------
__global__ __launch_bounds__(256) void mlp_kernel(const float* __restrict__ h,
                                                  const float* __restrict__ Wm1,
                                                  const float* __restrict__ bm1,
                                                  const float* __restrict__ Wm2,
                                                  const float* __restrict__ bm2,
                                                  float* __restrict__ out, int n) {
    const int lane = threadIdx.x & 63;
    const int node = blockIdx.x * 4 + (threadIdx.x >> 6);
    if (node >= n) return;
    const float* hr = h + (size_t)node * HC;
    float acc = bm1[lane];
#pragma unroll 8
    for (int k = 0; k < HC; ++k)
        acc = fmaf(hr[k], Wm1[k * 64 + lane], acc);
    acc = fmaxf(acc, 0.f);
    float o = acc * Wm2[lane];
#pragma unroll
    for (int off = 32; off; off >>= 1)
        o += __shfl_down(o, off);
    if (lane == 0) out[node] = o + bm2[0];
}

extern "C" void kernel_launch(void* const* d_in, const int* in_sizes, int n_in,
                              void* d_out, int out_size, void* d_ws, size_t ws_size,
                              hipStream_t stream) {
    const float* x   = (const float*)d_in[0];
    const int*   ei  = (const int*)  d_in[1];
    const float* W1  = (const float*)d_in[2];
    const float* b1  = (const float*)d_in[3];
    const float* g1  = (const float*)d_in[4];
    const float* be1 = (const float*)d_in[5];
    const float* W2  = (const float*)d_in[6];
    const float* b2  = (const float*)d_in[7];
    const float* g2  = (const float*)d_in[8];
    const float* be2 = (const float*)d_in[9];
    const float* Wm1 = (const float*)d_in[10];
    const float* bm1 = (const float*)d_in[11];
    const float* Wm2 = (const float*)d_in[12];
    const float* bm2 = (const float*)d_in[13];
    float* out = (float*)d_out;

    const int n = in_sizes[0] / HC;       // 100000
    const int E = in_sizes[1] / 2;        // 1600000
    const int* srcp = ei;
    const int* dstp = ei + E;

    char* ws = (char*)d_ws;
    size_t off = 0;
    auto alloc = [&](size_t bytes) { void* p = ws + off; off = (off + bytes + 511) & ~511ULL; return p; };
    float* dis    = (float*)alloc((size_t)n * 4);
    int*   degi   = (int*)  alloc((size_t)n * 4);
    int*   cursor = (int*)  alloc((size_t)n * 4);
    int*   rowptr = (int*)  alloc((size_t)(n + 1) * 4);
    int*   bsums  = (int*)  alloc(4096);
    int*   srcs   = (int*)  alloc((size_t)E * 4);
    float* coef   = (float*)alloc((size_t)E * 4);
    float* bufA   = (float*)alloc((size_t)n * HC * 4);
    float* bufB   = (float*)alloc((size_t)n * HC * 4);
    float* sums   = (float*)alloc(512);
    float* sumsq  = sums + 128;
    float* scale  = (float*)alloc(512);
    float* shift  = scale + 128;

    const int elemBlocks = (n * HC + 255) / 256;
    const int nodeBlocks = (n + 3) / 4;
    const int nScanBlocks = (n + 1023) / 1024;

    // ---- CSR build (once, shared by both layers) ----
    hipMemsetAsync(degi, 0, (size_t)n * 4, stream);
    degi_kernel<<<(E + 255) / 256, 256, 0, stream>>>(dstp, degi, E);
    dis_kernel<<<(n + 255) / 256, 256, 0, stream>>>(degi, dis, n);
    scan1<<<nScanBlocks, 256, 0, stream>>>(degi, cursor, bsums, n);
    scan2<<<1, 64, 0, stream>>>(bsums, nScanBlocks);
    scan3<<<(n + 256) / 256, 256, 0, stream>>>(cursor, bsums, rowptr, n, E);
    edge_place<<<(E + 255) / 256, 256, 0, stream>>>(srcp, dstp, dis, cursor, srcs, coef, E);

    // ---- layer 1 ----
    gemm128<<<(n + 63) / 64, 256, 0, stream>>>(x, W1, bufA, n);
    gcn_agg<<<nodeBlocks, 256, 0, stream>>>(bufA, srcs, coef, rowptr, dis, b1, bufB, n);
    hipMemsetAsync(sums, 0, 1024, stream);
    bn_stats<<<512, 256, 0, stream>>>(bufB, sums, sumsq, n);
    bn_finalize<<<1, 128, 0, stream>>>(sums, sumsq, g1, be1, scale, shift, n);
    bn_apply_relu<<<elemBlocks, 256, 0, stream>>>(bufB, scale, shift, n);

    // ---- layer 2 ----
    gemm128<<<(n + 63) / 64, 256, 0, stream>>>(bufB, W2, bufA, n);
    gcn_agg<<<nodeBlocks, 256, 0, stream>>>(bufA, srcs, coef, rowptr, dis, b2, bufB, n);
    hipMemsetAsync(sums, 0, 1024, stream);
    bn_stats<<<512, 256, 0, stream>>>(bufB, sums, sumsq, n);
    bn_finalize<<<1, 128, 0, stream>>>(sums, sumsq, g2, be2, scale, shift, n);
    bn_apply_relu<<<elemBlocks, 256, 0, stream>>>(bufB, scale, shift, n);

    // ---- MLP head ----
    mlp_kernel<<<nodeBlocks, 256, 0, stream>>>(bufB, Wm1, bm1, Wm2, bm2, out, n);
}

// Round 3
// 991.640 us; speedup vs baseline: 2.3682x; 1.3592x over previous
//
#include <hip/hip_runtime.h>
#include <hip/hip_fp16.h>

#define HC 128
#define EPS_BN 1e-5f

// ---------------- degree count (int) ----------------
__global__ void degi_kernel(const int* __restrict__ dst, int* __restrict__ degi, int E) {
    int e = blockIdx.x * 256 + threadIdx.x;
    if (e < E) atomicAdd(&degi[dst[e]], 1);
}

__global__ void dis_kernel(const int* __restrict__ degi, float* __restrict__ dis, int n) {
    int i = blockIdx.x * 256 + threadIdx.x;
    if (i < n) dis[i] = rsqrtf((float)degi[i] + 1.0f);  // +1 self-loop
}

// ---------------- exclusive scan of degi -> rowptr ----------------
__global__ __launch_bounds__(256) void scan1(const int* __restrict__ degi, int* __restrict__ excl,
                                             int* __restrict__ bsums, int n) {
    __shared__ int ts[256];
    const int tid = threadIdx.x;
    const int base = blockIdx.x * 1024 + tid * 4;
    int v0 = 0, v1 = 0, v2 = 0, v3 = 0;
    if (base + 3 < n) {
        int4 v = *(const int4*)(degi + base);
        v0 = v.x; v1 = v.y; v2 = v.z; v3 = v.w;
    } else {
        if (base + 0 < n) v0 = degi[base + 0];
        if (base + 1 < n) v1 = degi[base + 1];
        if (base + 2 < n) v2 = degi[base + 2];
        if (base + 3 < n) v3 = degi[base + 3];
    }
    int p1 = v0, p2 = v0 + v1, p3 = v0 + v1 + v2, total = p3 + v3;
    ts[tid] = total;
    __syncthreads();
    for (int off = 1; off < 256; off <<= 1) {
        int t = (tid >= off) ? ts[tid - off] : 0;
        __syncthreads();
        ts[tid] += t;
        __syncthreads();
    }
    int eb = (tid ? ts[tid - 1] : 0);
    if (tid == 255) bsums[blockIdx.x] = ts[255];
    if (base + 0 < n) excl[base + 0] = eb;
    if (base + 1 < n) excl[base + 1] = eb + p1;
    if (base + 2 < n) excl[base + 2] = eb + p2;
    if (base + 3 < n) excl[base + 3] = eb + p3;
}

__global__ void scan2(int* __restrict__ bsums, int nb) {
    if (threadIdx.x == 0) {
        int s = 0;
        for (int i = 0; i < nb; ++i) { int t = bsums[i]; bsums[i] = s; s += t; }
    }
}

__global__ void scan3(int* __restrict__ cursor, const int* __restrict__ bsums,
                      int* __restrict__ rowptr, int n, int E) {
    int i = blockIdx.x * 256 + threadIdx.x;
    if (i < n) {
        int v = cursor[i] + bsums[i >> 10];
        rowptr[i] = v;
        cursor[i] = v;
    }
    if (i == n) rowptr[n] = E;
}

// ---------------- edge placement into CSR ----------------
__global__ void edge_place(const int* __restrict__ src, const int* __restrict__ dst,
                           const float* __restrict__ dis, int* __restrict__ cursor,
                           int* __restrict__ srcs, float* __restrict__ coef, int E) {
    int e = blockIdx.x * 256 + threadIdx.x;
    if (e < E) {
        int s = src[e], d = dst[e];
        int pos = atomicAdd(&cursor[d], 1);
        srcs[pos] = s;
        coef[pos] = dis[s] * dis[d];
    }
}

// ---------------- register-tiled GEMM: Yh[n,128] = T(X)[n,128] @ W[128,128] ----
// T = identity (doTrans=0) or relu(scale*x+shift) (doTrans=1). Output fp16.
// Block: 64 rows x 128 cols, 256 threads, 4x8 outputs/thread.
__global__ __launch_bounds__(256) void gemm128_f16(const float* __restrict__ X,
                                                   const float* __restrict__ W,
                                                   const float* __restrict__ scale,
                                                   const float* __restrict__ shift,
                                                   __half* __restrict__ Y, int n, int doTrans) {
    __shared__ float xs[64][HC + 4];
    const int tid  = threadIdx.x;
    const int row0 = blockIdx.x * 64;

    // stage X tile (optionally BN+ReLU transformed)
    for (int i = tid; i < 64 * 32; i += 256) {
        int r = i >> 5, kq = (i & 31) << 2;
        float4 v = make_float4(0.f, 0.f, 0.f, 0.f);
        if (row0 + r < n) {
            v = *(const float4*)(X + (size_t)(row0 + r) * HC + kq);
            if (doTrans) {
                float4 sc = *(const float4*)(scale + kq);
                float4 sh = *(const float4*)(shift + kq);
                v.x = fmaxf(fmaf(v.x, sc.x, sh.x), 0.f);
                v.y = fmaxf(fmaf(v.y, sc.y, sh.y), 0.f);
                v.z = fmaxf(fmaf(v.z, sc.z, sh.z), 0.f);
                v.w = fmaxf(fmaf(v.w, sc.w, sh.w), 0.f);
            }
        }
        *(float4*)&xs[r][kq] = v;
    }
    __syncthreads();

    const int cg = tid & 15;   // cols c0..c0+7
    const int rg = tid >> 4;   // rows r0..r0+3
    const int c0 = cg * 8;
    const int r0 = rg * 4;

    float acc[4][8];
#pragma unroll
    for (int i = 0; i < 4; ++i)
#pragma unroll
        for (int j = 0; j < 8; ++j) acc[i][j] = 0.f;

    for (int kk = 0; kk < HC; kk += 4) {
        float xv[4][4];
        *(float4*)xv[0] = *(const float4*)&xs[r0 + 0][kk];
        *(float4*)xv[1] = *(const float4*)&xs[r0 + 1][kk];
        *(float4*)xv[2] = *(const float4*)&xs[r0 + 2][kk];
        *(float4*)xv[3] = *(const float4*)&xs[r0 + 3][kk];
#pragma unroll
        for (int j = 0; j < 4; ++j) {
            float wv[8];
            *(float4*)&wv[0] = *(const float4*)(W + (size_t)(kk + j) * HC + c0);
            *(float4*)&wv[4] = *(const float4*)(W + (size_t)(kk + j) * HC + c0 + 4);
#pragma unroll
            for (int i = 0; i < 4; ++i)
#pragma unroll
                for (int c = 0; c < 8; ++c)
                    acc[i][c] = fmaf(xv[i][j], wv[c], acc[i][c]);
        }
    }

#pragma unroll
    for (int i = 0; i < 4; ++i) {
        int row = row0 + r0 + i;
        if (row < n) {
            union { uint4 u; __half2 h[4]; } pk;
            pk.h[0] = __floats2half2_rn(acc[i][0], acc[i][1]);
            pk.h[1] = __floats2half2_rn(acc[i][2], acc[i][3]);
            pk.h[2] = __floats2half2_rn(acc[i][4], acc[i][5]);
            pk.h[3] = __floats2half2_rn(acc[i][6], acc[i][7]);
            *(uint4*)(Y + (size_t)row * HC + c0) = pk.u;
        }
    }
}

// ---------------- CSR gather aggregation (fp16 rows, fp32 accumulate) --------
__global__ __launch_bounds__(256) void gcn_agg_f16(const __half* __restrict__ xw,
                                                   const int* __restrict__ srcs,
                                                   const float* __restrict__ coef,
                                                   const int* __restrict__ rowptr,
                                                   const float* __restrict__ dis,
                                                   const float* __restrict__ b,
                                                   float* __restrict__ out, int n) {
    const int node = blockIdx.x * 4 + (threadIdx.x >> 6);
    const int lane = threadIdx.x & 63;
    if (node >= n) return;
    const __half2* xw2 = (const __half2*)xw;
    float d = dis[node];
    float2 self = __half22float2(xw2[(size_t)node * 64 + lane]);
    float2 bb   = ((const float2*)b)[lane];
    float2 acc;
    acc.x = fmaf(self.x, d * d, bb.x);
    acc.y = fmaf(self.y, d * d, bb.y);
    const int e1 = rowptr[node + 1];
    for (int e = rowptr[node]; e < e1; ++e) {
        int s = srcs[e];
        float c = coef[e];
        float2 v = __half22float2(xw2[(size_t)s * 64 + lane]);
        acc.x = fmaf(v.x, c, acc.x);
        acc.y = fmaf(v.y, c, acc.y);
    }
    ((float2*)out)[(size_t)node * 64 + lane] = acc;
}

// ---------------- BatchNorm stats ----------------
__global__ __launch_bounds__(256) void bn_stats(const float* __restrict__ x,
                                                float* __restrict__ sums,
                                                float* __restrict__ sumsq, int n) {
    __shared__ float ss[256], sq[256];
    const int tid = threadIdx.x;
    const int c = tid & 127, half = tid >> 7;
    float s = 0.f, q = 0.f;
    for (int r = blockIdx.x * 2 + half; r < n; r += gridDim.x * 2) {
        float v = x[(size_t)r * HC + c];
        s += v; q += v * v;
    }
    ss[tid] = s; sq[tid] = q;
    __syncthreads();
    if (half == 0) {
        atomicAdd(&sums[c],  ss[tid] + ss[tid + 128]);
        atomicAdd(&sumsq[c], sq[tid] + sq[tid + 128]);
    }
}

__global__ void bn_finalize(const float* __restrict__ sums, const float* __restrict__ sumsq,
                            const float* __restrict__ g, const float* __restrict__ be,
                            float* __restrict__ scale, float* __restrict__ shift, int n) {
    int c = threadIdx.x;
    float m = sums[c] / (float)n;
    float v = sumsq[c] / (float)n - m * m;
    float sc = g[c] * rsqrtf(fmaxf(v, 0.f) + EPS_BN);
    scale[c] = sc;
    shift[c] = be[c] - m * sc;
}

// ---------------- fused MLP head (BN2 apply + ReLU folded in) ----------------
__global__ __launch_bounds__(256) void mlp_kernel(const float* __restrict__ h,
                                                  const float* __restrict__ scale,
                                                  const float* __restrict__ shift,
                                                  const float* __restrict__ Wm1,
                                                  const float* __restrict__ bm1,
                                                  const float* __restrict__ Wm2,
                                                  const float* __restrict__ bm2,
                                                  float* __restrict__ out, int n) {
    __shared__ float sc[HC], sh[HC], w2s[64];
    const int tid = threadIdx.x;
    if (tid < HC) { sc[tid] = scale[tid]; sh[tid] = shift[tid]; }
    if (tid < 64) w2s[tid] = Wm2[tid];
    __syncthreads();
    const int lane = tid & 63;
    const int node = blockIdx.x * 4 + (tid >> 6);
    if (node >= n) return;
    const float* hr = h + (size_t)node * HC;
    float acc = bm1[lane];
#pragma unroll 8
    for (int k = 0; k < HC; ++k) {
        float t = fmaxf(fmaf(hr[k], sc[k], sh[k]), 0.f);
        acc = fmaf(t, Wm1[k * 64 + lane], acc);
    }
    acc = fmaxf(acc, 0.f);
    float o = acc * w2s[lane];
#pragma unroll
    for (int off = 32; off; off >>= 1)
        o += __shfl_down(o, off);
    if (lane == 0) out[node] = o + bm2[0];
}

extern "C" void kernel_launch(void* const* d_in, const int* in_sizes, int n_in,
                              void* d_out, int out_size, void* d_ws, size_t ws_size,
                              hipStream_t stream) {
    const float* x   = (const float*)d_in[0];
    const int*   ei  = (const int*)  d_in[1];
    const float* W1  = (const float*)d_in[2];
    const float* b1  = (const float*)d_in[3];
    const float* g1  = (const float*)d_in[4];
    const float* be1 = (const float*)d_in[5];
    const float* W2  = (const float*)d_in[6];
    const float* b2  = (const float*)d_in[7];
    const float* g2  = (const float*)d_in[8];
    const float* be2 = (const float*)d_in[9];
    const float* Wm1 = (const float*)d_in[10];
    const float* bm1 = (const float*)d_in[11];
    const float* Wm2 = (const float*)d_in[12];
    const float* bm2 = (const float*)d_in[13];
    float* out = (float*)d_out;

    const int n = in_sizes[0] / HC;       // 100000
    const int E = in_sizes[1] / 2;        // 1600000
    const int* srcp = ei;
    const int* dstp = ei + E;

    char* ws = (char*)d_ws;
    size_t off = 0;
    auto alloc = [&](size_t bytes) { void* p = ws + off; off = (off + bytes + 511) & ~511ULL; return p; };
    float*  dis    = (float*) alloc((size_t)n * 4);
    int*    degi   = (int*)   alloc((size_t)n * 4);
    int*    cursor = (int*)   alloc((size_t)n * 4);
    int*    rowptr = (int*)   alloc((size_t)(n + 1) * 4);
    int*    bsums  = (int*)   alloc(4096);
    int*    srcs   = (int*)   alloc((size_t)E * 4);
    float*  coef   = (float*) alloc((size_t)E * 4);
    __half* xwh    = (__half*)alloc((size_t)n * HC * 2);
    float*  bufB   = (float*) alloc((size_t)n * HC * 4);
    float*  sums   = (float*) alloc(512);
    float*  sumsq  = sums + 128;
    float*  scale1 = (float*) alloc(512);
    float*  shift1 = scale1 + 128;
    float*  scale2 = (float*) alloc(512);
    float*  shift2 = scale2 + 128;

    const int nodeBlocks  = (n + 3) / 4;
    const int gemmBlocks  = (n + 63) / 64;
    const int nScanBlocks = (n + 1023) / 1024;

    // ---- CSR build (shared by both layers) ----
    hipMemsetAsync(degi, 0, (size_t)n * 4, stream);
    degi_kernel<<<(E + 255) / 256, 256, 0, stream>>>(dstp, degi, E);
    dis_kernel<<<(n + 255) / 256, 256, 0, stream>>>(degi, dis, n);
    scan1<<<nScanBlocks, 256, 0, stream>>>(degi, cursor, bsums, n);
    scan2<<<1, 64, 0, stream>>>(bsums, nScanBlocks);
    scan3<<<(n + 256) / 256, 256, 0, stream>>>(cursor, bsums, rowptr, n, E);
    edge_place<<<(E + 255) / 256, 256, 0, stream>>>(srcp, dstp, dis, cursor, srcs, coef, E);

    // ---- layer 1 ----
    gemm128_f16<<<gemmBlocks, 256, 0, stream>>>(x, W1, nullptr, nullptr, xwh, n, 0);
    gcn_agg_f16<<<nodeBlocks, 256, 0, stream>>>(xwh, srcs, coef, rowptr, dis, b1, bufB, n);
    hipMemsetAsync(sums, 0, 1024, stream);
    bn_stats<<<512, 256, 0, stream>>>(bufB, sums, sumsq, n);
    bn_finalize<<<1, 128, 0, stream>>>(sums, sumsq, g1, be1, scale1, shift1, n);

    // ---- layer 2 (BN1+ReLU fused into GEMM input) ----
    gemm128_f16<<<gemmBlocks, 256, 0, stream>>>(bufB, W2, scale1, shift1, xwh, n, 1);
    gcn_agg_f16<<<nodeBlocks, 256, 0, stream>>>(xwh, srcs, coef, rowptr, dis, b2, bufB, n);
    hipMemsetAsync(sums, 0, 1024, stream);
    bn_stats<<<512, 256, 0, stream>>>(bufB, sums, sumsq, n);
    bn_finalize<<<1, 128, 0, stream>>>(sums, sumsq, g2, be2, scale2, shift2, n);

    // ---- MLP head (BN2+ReLU fused) ----
    mlp_kernel<<<nodeBlocks, 256, 0, stream>>>(bufB, scale2, shift2, Wm1, bm1, Wm2, bm2, out, n);
}

// Round 4
// 711.592 us; speedup vs baseline: 3.3002x; 1.3936x over previous
//
#include <hip/hip_runtime.h>
#include <hip/hip_fp16.h>

#define HC 128
#define EPS_BN 1e-5f

// ---------------- degree count (int) ----------------
__global__ void degi_kernel(const int* __restrict__ dst, int* __restrict__ degi, int E) {
    int e = blockIdx.x * 256 + threadIdx.x;
    if (e < E) atomicAdd(&degi[dst[e]], 1);
}

__global__ void dis_kernel(const int* __restrict__ degi, float* __restrict__ dis, int n) {
    int i = blockIdx.x * 256 + threadIdx.x;
    if (i < n) dis[i] = rsqrtf((float)degi[i] + 1.0f);  // +1 self-loop
}

// ---------------- exclusive scan of degi -> rowptr ----------------
__global__ __launch_bounds__(256) void scan1(const int* __restrict__ degi, int* __restrict__ excl,
                                             int* __restrict__ bsums, int n) {
    __shared__ int ts[256];
    const int tid = threadIdx.x;
    const int base = blockIdx.x * 1024 + tid * 4;
    int v0 = 0, v1 = 0, v2 = 0, v3 = 0;
    if (base + 3 < n) {
        int4 v = *(const int4*)(degi + base);
        v0 = v.x; v1 = v.y; v2 = v.z; v3 = v.w;
    } else {
        if (base + 0 < n) v0 = degi[base + 0];
        if (base + 1 < n) v1 = degi[base + 1];
        if (base + 2 < n) v2 = degi[base + 2];
        if (base + 3 < n) v3 = degi[base + 3];
    }
    int p1 = v0, p2 = v0 + v1, p3 = v0 + v1 + v2, total = p3 + v3;
    ts[tid] = total;
    __syncthreads();
    for (int off = 1; off < 256; off <<= 1) {
        int t = (tid >= off) ? ts[tid - off] : 0;
        __syncthreads();
        ts[tid] += t;
        __syncthreads();
    }
    int eb = (tid ? ts[tid - 1] : 0);
    if (tid == 255) bsums[blockIdx.x] = ts[255];
    if (base + 0 < n) excl[base + 0] = eb;
    if (base + 1 < n) excl[base + 1] = eb + p1;
    if (base + 2 < n) excl[base + 2] = eb + p2;
    if (base + 3 < n) excl[base + 3] = eb + p3;
}

__global__ void scan2(int* __restrict__ bsums, int nb) {
    if (threadIdx.x == 0) {
        int s = 0;
        for (int i = 0; i < nb; ++i) { int t = bsums[i]; bsums[i] = s; s += t; }
    }
}

__global__ void scan3(int* __restrict__ cursor, const int* __restrict__ bsums,
                      int* __restrict__ rowptr, int n, int E) {
    int i = blockIdx.x * 256 + threadIdx.x;
    if (i < n) {
        int v = cursor[i] + bsums[i >> 10];
        rowptr[i] = v;
        cursor[i] = v;
    }
    if (i == n) rowptr[n] = E;
}

// ---------------- edge placement into CSR (packed src+coef) ----------------
__global__ void edge_place(const int* __restrict__ src, const int* __restrict__ dst,
                           const float* __restrict__ dis, int* __restrict__ cursor,
                           int2* __restrict__ ep, int E) {
    int e = blockIdx.x * 256 + threadIdx.x;
    if (e < E) {
        int s = src[e], d = dst[e];
        int pos = atomicAdd(&cursor[d], 1);
        ep[pos] = make_int2(s, __float_as_int(dis[s] * dis[d]));
    }
}

// ---------------- register-tiled GEMM: Yh[n,128] = T(X)[n,128] @ W[128,128] ----
__global__ __launch_bounds__(256) void gemm128_f16(const float* __restrict__ X,
                                                   const float* __restrict__ W,
                                                   const float* __restrict__ scale,
                                                   const float* __restrict__ shift,
                                                   __half* __restrict__ Y, int n, int doTrans) {
    __shared__ float xs[64][HC + 4];
    const int tid  = threadIdx.x;
    const int row0 = blockIdx.x * 64;

    for (int i = tid; i < 64 * 32; i += 256) {
        int r = i >> 5, kq = (i & 31) << 2;
        float4 v = make_float4(0.f, 0.f, 0.f, 0.f);
        if (row0 + r < n) {
            v = *(const float4*)(X + (size_t)(row0 + r) * HC + kq);
            if (doTrans) {
                float4 sc = *(const float4*)(scale + kq);
                float4 sh = *(const float4*)(shift + kq);
                v.x = fmaxf(fmaf(v.x, sc.x, sh.x), 0.f);
                v.y = fmaxf(fmaf(v.y, sc.y, sh.y), 0.f);
                v.z = fmaxf(fmaf(v.z, sc.z, sh.z), 0.f);
                v.w = fmaxf(fmaf(v.w, sc.w, sh.w), 0.f);
            }
        }
        *(float4*)&xs[r][kq] = v;
    }
    __syncthreads();

    const int cg = tid & 15;
    const int rg = tid >> 4;
    const int c0 = cg * 8;
    const int r0 = rg * 4;

    float acc[4][8];
#pragma unroll
    for (int i = 0; i < 4; ++i)
#pragma unroll
        for (int j = 0; j < 8; ++j) acc[i][j] = 0.f;

    for (int kk = 0; kk < HC; kk += 4) {
        float xv[4][4];
        *(float4*)xv[0] = *(const float4*)&xs[r0 + 0][kk];
        *(float4*)xv[1] = *(const float4*)&xs[r0 + 1][kk];
        *(float4*)xv[2] = *(const float4*)&xs[r0 + 2][kk];
        *(float4*)xv[3] = *(const float4*)&xs[r0 + 3][kk];
#pragma unroll
        for (int j = 0; j < 4; ++j) {
            float wv[8];
            *(float4*)&wv[0] = *(const float4*)(W + (size_t)(kk + j) * HC + c0);
            *(float4*)&wv[4] = *(const float4*)(W + (size_t)(kk + j) * HC + c0 + 4);
#pragma unroll
            for (int i = 0; i < 4; ++i)
#pragma unroll
                for (int c = 0; c < 8; ++c)
                    acc[i][c] = fmaf(xv[i][j], wv[c], acc[i][c]);
        }
    }

#pragma unroll
    for (int i = 0; i < 4; ++i) {
        int row = row0 + r0 + i;
        if (row < n) {
            union { uint4 u; __half2 h[4]; } pk;
            pk.h[0] = __floats2half2_rn(acc[i][0], acc[i][1]);
            pk.h[1] = __floats2half2_rn(acc[i][2], acc[i][3]);
            pk.h[2] = __floats2half2_rn(acc[i][4], acc[i][5]);
            pk.h[3] = __floats2half2_rn(acc[i][6], acc[i][7]);
            *(uint4*)(Y + (size_t)row * HC + c0) = pk.u;
        }
    }
}

// ---------------- CSR gather aggregation (fp16 rows, fp32 acc, unroll-2) -----
__global__ __launch_bounds__(256) void gcn_agg_f16(const __half* __restrict__ xw,
                                                   const int2* __restrict__ ep,
                                                   const int* __restrict__ rowptr,
                                                   const float* __restrict__ dis,
                                                   const float* __restrict__ b,
                                                   float* __restrict__ out, int n) {
    const int node = blockIdx.x * 4 + (threadIdx.x >> 6);
    const int lane = threadIdx.x & 63;
    if (node >= n) return;
    const __half2* xw2 = (const __half2*)xw;
    float d = dis[node];
    float2 self = __half22float2(xw2[(size_t)node * 64 + lane]);
    float2 bb   = ((const float2*)b)[lane];
    float2 acc;
    acc.x = fmaf(self.x, d * d, bb.x);
    acc.y = fmaf(self.y, d * d, bb.y);
    int e  = rowptr[node];
    const int e1 = rowptr[node + 1];
    for (; e + 2 <= e1; e += 2) {
        int2 p0 = ep[e], p1 = ep[e + 1];
        float2 v0 = __half22float2(xw2[(size_t)p0.x * 64 + lane]);
        float2 v1 = __half22float2(xw2[(size_t)p1.x * 64 + lane]);
        float c0 = __int_as_float(p0.y), c1 = __int_as_float(p1.y);
        acc.x = fmaf(v0.x, c0, acc.x);
        acc.y = fmaf(v0.y, c0, acc.y);
        acc.x = fmaf(v1.x, c1, acc.x);
        acc.y = fmaf(v1.y, c1, acc.y);
    }
    if (e < e1) {
        int2 p0 = ep[e];
        float2 v0 = __half22float2(xw2[(size_t)p0.x * 64 + lane]);
        float c0 = __int_as_float(p0.y);
        acc.x = fmaf(v0.x, c0, acc.x);
        acc.y = fmaf(v0.y, c0, acc.y);
    }
    ((float2*)out)[(size_t)node * 64 + lane] = acc;
}

// ---------------- BatchNorm stats ----------------
__global__ __launch_bounds__(256) void bn_stats(const float* __restrict__ x,
                                                float* __restrict__ sums,
                                                float* __restrict__ sumsq, int n) {
    __shared__ float ss[256], sq[256];
    const int tid = threadIdx.x;
    const int c = tid & 127, half = tid >> 7;
    float s = 0.f, q = 0.f;
    for (int r = blockIdx.x * 2 + half; r < n; r += gridDim.x * 2) {
        float v = x[(size_t)r * HC + c];
        s += v; q += v * v;
    }
    ss[tid] = s; sq[tid] = q;
    __syncthreads();
    if (half == 0) {
        atomicAdd(&sums[c],  ss[tid] + ss[tid + 128]);
        atomicAdd(&sumsq[c], sq[tid] + sq[tid + 128]);
    }
}

__global__ void bn_finalize(const float* __restrict__ sums, const float* __restrict__ sumsq,
                            const float* __restrict__ g, const float* __restrict__ be,
                            float* __restrict__ scale, float* __restrict__ shift, int n) {
    int c = threadIdx.x;
    float m = sums[c] / (float)n;
    float v = sumsq[c] / (float)n - m * m;
    float sc = g[c] * rsqrtf(fmaxf(v, 0.f) + EPS_BN);
    scale[c] = sc;
    shift[c] = be[c] - m * sc;
}

// ---------------- MLP head as register-tiled GEMM (BN2+ReLU fused) ----------
// Block: 64 nodes, 256 threads; thread = 4 nodes x 4 hidden; layer-2 folded.
__global__ __launch_bounds__(256) void mlp_gemm(const float* __restrict__ h,
                                                const float* __restrict__ scale,
                                                const float* __restrict__ shift,
                                                const float* __restrict__ Wm1,
                                                const float* __restrict__ bm1,
                                                const float* __restrict__ Wm2,
                                                const float* __restrict__ bm2,
                                                float* __restrict__ out, int n) {
    __shared__ float hs[64][HC + 4];
    __shared__ float red[64][17];
    const int tid  = threadIdx.x;
    const int row0 = blockIdx.x * 64;

    // stage H tile with BN2 + ReLU applied
    for (int i = tid; i < 64 * 32; i += 256) {
        int r = i >> 5, kq = (i & 31) << 2;
        float4 v = make_float4(0.f, 0.f, 0.f, 0.f);
        if (row0 + r < n) {
            v = *(const float4*)(h + (size_t)(row0 + r) * HC + kq);
            float4 sc = *(const float4*)(scale + kq);
            float4 sh = *(const float4*)(shift + kq);
            v.x = fmaxf(fmaf(v.x, sc.x, sh.x), 0.f);
            v.y = fmaxf(fmaf(v.y, sc.y, sh.y), 0.f);
            v.z = fmaxf(fmaf(v.z, sc.z, sh.z), 0.f);
            v.w = fmaxf(fmaf(v.w, sc.w, sh.w), 0.f);
        }
        *(float4*)&hs[r][kq] = v;
    }
    __syncthreads();

    const int cg = tid & 15;     // hidden group: 4 cols
    const int rg = tid >> 4;     // row group: 4 rows
    const int c0 = cg * 4;
    const int r0 = rg * 4;

    float acc[4][4];
#pragma unroll
    for (int i = 0; i < 4; ++i)
#pragma unroll
        for (int j = 0; j < 4; ++j) acc[i][j] = 0.f;

    for (int kk = 0; kk < HC; kk += 4) {
        float xv[4][4];
        *(float4*)xv[0] = *(const float4*)&hs[r0 + 0][kk];
        *(float4*)xv[1] = *(const float4*)&hs[r0 + 1][kk];
        *(float4*)xv[2] = *(const float4*)&hs[r0 + 2][kk];
        *(float4*)xv[3] = *(const float4*)&hs[r0 + 3][kk];
#pragma unroll
        for (int j = 0; j < 4; ++j) {
            float wv[4];
            *(float4*)wv = *(const float4*)(Wm1 + (size_t)(kk + j) * 64 + c0);
#pragma unroll
            for (int i = 0; i < 4; ++i)
#pragma unroll
                for (int c = 0; c < 4; ++c)
                    acc[i][c] = fmaf(xv[i][j], wv[c], acc[i][c]);
        }
    }

    float4 b1v = *(const float4*)(bm1 + c0);
    float4 w2v = *(const float4*)(Wm2 + c0);
#pragma unroll
    for (int i = 0; i < 4; ++i) {
        float t0 = fmaxf(acc[i][0] + b1v.x, 0.f) * w2v.x;
        float t1 = fmaxf(acc[i][1] + b1v.y, 0.f) * w2v.y;
        float t2 = fmaxf(acc[i][2] + b1v.z, 0.f) * w2v.z;
        float t3 = fmaxf(acc[i][3] + b1v.w, 0.f) * w2v.w;
        red[r0 + i][cg] = (t0 + t1) + (t2 + t3);
    }
    __syncthreads();

    if (tid < 64 && row0 + tid < n) {
        float s = 0.f;
#pragma unroll
        for (int g = 0; g < 16; ++g) s += red[tid][g];
        out[row0 + tid] = s + bm2[0];
    }
}

extern "C" void kernel_launch(void* const* d_in, const int* in_sizes, int n_in,
                              void* d_out, int out_size, void* d_ws, size_t ws_size,
                              hipStream_t stream) {
    const float* x   = (const float*)d_in[0];
    const int*   ei  = (const int*)  d_in[1];
    const float* W1  = (const float*)d_in[2];
    const float* b1  = (const float*)d_in[3];
    const float* g1  = (const float*)d_in[4];
    const float* be1 = (const float*)d_in[5];
    const float* W2  = (const float*)d_in[6];
    const float* b2  = (const float*)d_in[7];
    const float* g2  = (const float*)d_in[8];
    const float* be2 = (const float*)d_in[9];
    const float* Wm1 = (const float*)d_in[10];
    const float* bm1 = (const float*)d_in[11];
    const float* Wm2 = (const float*)d_in[12];
    const float* bm2 = (const float*)d_in[13];
    float* out = (float*)d_out;

    const int n = in_sizes[0] / HC;       // 100000
    const int E = in_sizes[1] / 2;        // 1600000
    const int* srcp = ei;
    const int* dstp = ei + E;

    char* ws = (char*)d_ws;
    size_t off = 0;
    auto alloc = [&](size_t bytes) { void* p = ws + off; off = (off + bytes + 511) & ~511ULL; return p; };
    float*  dis    = (float*) alloc((size_t)n * 4);
    int*    degi   = (int*)   alloc((size_t)n * 4);
    int*    cursor = (int*)   alloc((size_t)n * 4);
    int*    rowptr = (int*)   alloc((size_t)(n + 1) * 4);
    int*    bsums  = (int*)   alloc(4096);
    int2*   ep     = (int2*)  alloc((size_t)E * 8);
    __half* xwh    = (__half*)alloc((size_t)n * HC * 2);
    float*  bufB   = (float*) alloc((size_t)n * HC * 4);
    float*  sums   = (float*) alloc(512);
    float*  sumsq  = sums + 128;
    float*  scale1 = (float*) alloc(512);
    float*  shift1 = scale1 + 128;
    float*  scale2 = (float*) alloc(512);
    float*  shift2 = scale2 + 128;

    const int nodeBlocks  = (n + 3) / 4;
    const int gemmBlocks  = (n + 63) / 64;
    const int nScanBlocks = (n + 1023) / 1024;

    // ---- CSR build (shared by both layers) ----
    hipMemsetAsync(degi, 0, (size_t)n * 4, stream);
    degi_kernel<<<(E + 255) / 256, 256, 0, stream>>>(dstp, degi, E);
    dis_kernel<<<(n + 255) / 256, 256, 0, stream>>>(degi, dis, n);
    scan1<<<nScanBlocks, 256, 0, stream>>>(degi, cursor, bsums, n);
    scan2<<<1, 64, 0, stream>>>(bsums, nScanBlocks);
    scan3<<<(n + 256) / 256, 256, 0, stream>>>(cursor, bsums, rowptr, n, E);
    edge_place<<<(E + 255) / 256, 256, 0, stream>>>(srcp, dstp, dis, cursor, ep, E);

    // ---- layer 1 ----
    gemm128_f16<<<gemmBlocks, 256, 0, stream>>>(x, W1, nullptr, nullptr, xwh, n, 0);
    gcn_agg_f16<<<nodeBlocks, 256, 0, stream>>>(xwh, ep, rowptr, dis, b1, bufB, n);
    hipMemsetAsync(sums, 0, 1024, stream);
    bn_stats<<<512, 256, 0, stream>>>(bufB, sums, sumsq, n);
    bn_finalize<<<1, 128, 0, stream>>>(sums, sumsq, g1, be1, scale1, shift1, n);

    // ---- layer 2 (BN1+ReLU fused into GEMM input) ----
    gemm128_f16<<<gemmBlocks, 256, 0, stream>>>(bufB, W2, scale1, shift1, xwh, n, 1);
    gcn_agg_f16<<<nodeBlocks, 256, 0, stream>>>(xwh, ep, rowptr, dis, b2, bufB, n);
    hipMemsetAsync(sums, 0, 1024, stream);
    bn_stats<<<512, 256, 0, stream>>>(bufB, sums, sumsq, n);
    bn_finalize<<<1, 128, 0, stream>>>(sums, sumsq, g2, be2, scale2, shift2, n);

    // ---- MLP head (BN2+ReLU fused, tiled GEMM) ----
    mlp_gemm<<<gemmBlocks, 256, 0, stream>>>(bufB, scale2, shift2, Wm1, bm1, Wm2, bm2, out, n);
}

// Round 5
// 705.176 us; speedup vs baseline: 3.3303x; 1.0091x over previous
//
#include <hip/hip_runtime.h>
#include <hip/hip_fp16.h>

#define HC 128
#define EPS_BN 1e-5f

typedef _Float16 f16;
typedef f16  f16x8 __attribute__((ext_vector_type(8)));
typedef float f32x4 __attribute__((ext_vector_type(4)));

// ---------------- degree count (int) ----------------
__global__ void degi_kernel(const int* __restrict__ dst, int* __restrict__ degi, int E) {
    int e = blockIdx.x * 256 + threadIdx.x;
    if (e < E) atomicAdd(&degi[dst[e]], 1);
}

__global__ void dis_kernel(const int* __restrict__ degi, float* __restrict__ dis, int n) {
    int i = blockIdx.x * 256 + threadIdx.x;
    if (i < n) dis[i] = rsqrtf((float)degi[i] + 1.0f);  // +1 self-loop
}

// ---------------- exclusive scan of degi -> rowptr ----------------
__global__ __launch_bounds__(256) void scan1(const int* __restrict__ degi, int* __restrict__ excl,
                                             int* __restrict__ bsums, int n) {
    __shared__ int ts[256];
    const int tid = threadIdx.x;
    const int base = blockIdx.x * 1024 + tid * 4;
    int v0 = 0, v1 = 0, v2 = 0, v3 = 0;
    if (base + 3 < n) {
        int4 v = *(const int4*)(degi + base);
        v0 = v.x; v1 = v.y; v2 = v.z; v3 = v.w;
    } else {
        if (base + 0 < n) v0 = degi[base + 0];
        if (base + 1 < n) v1 = degi[base + 1];
        if (base + 2 < n) v2 = degi[base + 2];
        if (base + 3 < n) v3 = degi[base + 3];
    }
    int p1 = v0, p2 = v0 + v1, p3 = v0 + v1 + v2, total = p3 + v3;
    ts[tid] = total;
    __syncthreads();
    for (int off = 1; off < 256; off <<= 1) {
        int t = (tid >= off) ? ts[tid - off] : 0;
        __syncthreads();
        ts[tid] += t;
        __syncthreads();
    }
    int eb = (tid ? ts[tid - 1] : 0);
    if (tid == 255) bsums[blockIdx.x] = ts[255];
    if (base + 0 < n) excl[base + 0] = eb;
    if (base + 1 < n) excl[base + 1] = eb + p1;
    if (base + 2 < n) excl[base + 2] = eb + p2;
    if (base + 3 < n) excl[base + 3] = eb + p3;
}

__global__ void scan2(int* __restrict__ bsums, int nb) {
    if (threadIdx.x == 0) {
        int s = 0;
        for (int i = 0; i < nb; ++i) { int t = bsums[i]; bsums[i] = s; s += t; }
    }
}

__global__ void scan3(int* __restrict__ cursor, const int* __restrict__ bsums,
                      int* __restrict__ rowptr, int n, int E) {
    int i = blockIdx.x * 256 + threadIdx.x;
    if (i < n) {
        int v = cursor[i] + bsums[i >> 10];
        rowptr[i] = v;
        cursor[i] = v;
    }
    if (i == n) rowptr[n] = E;
}

// ---------------- edge placement into CSR (packed src+coef) ----------------
__global__ void edge_place(const int* __restrict__ src, const int* __restrict__ dst,
                           const float* __restrict__ dis, int* __restrict__ cursor,
                           int2* __restrict__ ep, int E) {
    int e = blockIdx.x * 256 + threadIdx.x;
    if (e < E) {
        int s = src[e], d = dst[e];
        int pos = atomicAdd(&cursor[d], 1);
        ep[pos] = make_int2(s, __float_as_int(dis[s] * dis[d]));
    }
}

// ---------------- W transpose + fp16 convert: Wt[c][k] = W[k][c] ------------
__global__ void wprep(const float* __restrict__ W, f16* __restrict__ Wt) {
    int idx = blockIdx.x * 256 + threadIdx.x;   // 16384 total
    if (idx < HC * HC) {
        int k = idx >> 7, c = idx & 127;
        Wt[(size_t)c * HC + k] = (f16)W[idx];
    }
}

// ---------------- MFMA GEMM: Y[n,128](f16) = T(X)[n,128] @ W[128,128] -------
// Wt is fp16 transposed weights [c][k]. SRC_F16: X is fp16. TRANS: BN+ReLU on X.
// Block: 64 rows, 256 threads (4 waves); wave computes 16 rows x 128 cols.
template<int SRC_F16, int TRANS>
__global__ __launch_bounds__(256) void gemm_mfma(const void* __restrict__ Xv,
                                                 const f16* __restrict__ Wt,
                                                 const float* __restrict__ scale,
                                                 const float* __restrict__ shift,
                                                 f16* __restrict__ Y, int n) {
    __shared__ f16 Ah[64][136];    // pad 8 halves: row stride 272 B
    __shared__ f16 Bh[128][136];   // Bh[c][k]
    const int tid  = threadIdx.x;
    const int row0 = blockIdx.x * 64;

    // stage B (Wt -> LDS), 2048 groups of 8 halves
#pragma unroll
    for (int i = 0; i < 8; ++i) {
        int idx = i * 256 + tid;
        int r = idx >> 4, g = idx & 15;
        *(f16x8*)&Bh[r][g * 8] = *(const f16x8*)(Wt + (size_t)r * HC + g * 8);
    }
    // stage A (X -> fp16 LDS, optional BN+ReLU), 1024 groups
#pragma unroll
    for (int i = 0; i < 4; ++i) {
        int idx = i * 256 + tid;
        int r = idx >> 4, g = idx & 15;
        int grow = row0 + r;
        f16x8 h = {};
        if (grow < n) {
            if constexpr (SRC_F16) {
                f16x8 v = *(const f16x8*)((const f16*)Xv + (size_t)grow * HC + g * 8);
                if constexpr (TRANS) {
#pragma unroll
                    for (int j = 0; j < 8; ++j) {
                        float f = (float)v[j];
                        f = fmaxf(fmaf(f, scale[g * 8 + j], shift[g * 8 + j]), 0.f);
                        h[j] = (f16)f;
                    }
                } else h = v;
            } else {
                const float* X = (const float*)Xv;
                float4 a = *(const float4*)(X + (size_t)grow * HC + g * 8);
                float4 c = *(const float4*)(X + (size_t)grow * HC + g * 8 + 4);
                if constexpr (TRANS) {
                    float4 sa = *(const float4*)(scale + g * 8);
                    float4 sb = *(const float4*)(scale + g * 8 + 4);
                    float4 ha = *(const float4*)(shift + g * 8);
                    float4 hb = *(const float4*)(shift + g * 8 + 4);
                    a.x = fmaxf(fmaf(a.x, sa.x, ha.x), 0.f);
                    a.y = fmaxf(fmaf(a.y, sa.y, ha.y), 0.f);
                    a.z = fmaxf(fmaf(a.z, sa.z, ha.z), 0.f);
                    a.w = fmaxf(fmaf(a.w, sa.w, ha.w), 0.f);
                    c.x = fmaxf(fmaf(c.x, sb.x, hb.x), 0.f);
                    c.y = fmaxf(fmaf(c.y, sb.y, hb.y), 0.f);
                    c.z = fmaxf(fmaf(c.z, sb.z, hb.z), 0.f);
                    c.w = fmaxf(fmaf(c.w, sb.w, hb.w), 0.f);
                }
                h[0] = (f16)a.x; h[1] = (f16)a.y; h[2] = (f16)a.z; h[3] = (f16)a.w;
                h[4] = (f16)c.x; h[5] = (f16)c.y; h[6] = (f16)c.z; h[7] = (f16)c.w;
            }
        }
        *(f16x8*)&Ah[r][g * 8] = h;
    }
    __syncthreads();

    const int wv   = tid >> 6;
    const int lane = tid & 63;
    const int m    = lane & 15;          // row within tile / col within D tile
    const int kq   = (lane >> 4) * 8;    // quad k offset

    f32x4 acc[8] = {};
#pragma unroll
    for (int kc = 0; kc < HC; kc += 32) {
        f16x8 a = *(const f16x8*)&Ah[wv * 16 + m][kc + kq];
#pragma unroll
        for (int t = 0; t < 8; ++t) {
            f16x8 b = *(const f16x8*)&Bh[t * 16 + m][kc + kq];
            acc[t] = __builtin_amdgcn_mfma_f32_16x16x32_f16(a, b, acc[t], 0, 0, 0);
        }
    }

    // epilogue: D col = lane&15, row = (lane>>4)*4 + reg
    const int rbase = row0 + wv * 16 + (lane >> 4) * 4;
#pragma unroll
    for (int t = 0; t < 8; ++t) {
#pragma unroll
        for (int r = 0; r < 4; ++r) {
            int grow = rbase + r;
            if (grow < n)
                Y[(size_t)grow * HC + t * 16 + m] = (f16)acc[t][r];
        }
    }
}

// ---------------- CSR gather agg (fp16 in/out, fused BN stats) ---------------
__global__ __launch_bounds__(256) void gcn_agg_f16(const __half* __restrict__ xw,
                                                   const int2* __restrict__ ep,
                                                   const int* __restrict__ rowptr,
                                                   const float* __restrict__ dis,
                                                   const float* __restrict__ bias,
                                                   __half* __restrict__ out,
                                                   float* __restrict__ sums,
                                                   float* __restrict__ sumsq,
                                                   int n, int nwaves) {
    __shared__ float4 red[4][64];
    const int wv   = threadIdx.x >> 6;
    const int lane = threadIdx.x & 63;
    const __half2* xw2 = (const __half2*)xw;
    float2 bb = ((const float2*)bias)[lane];
    float2 s = make_float2(0.f, 0.f), q = make_float2(0.f, 0.f);

    for (int node = blockIdx.x * 4 + wv; node < n; node += nwaves) {
        float d = dis[node];
        float2 self = __half22float2(xw2[(size_t)node * 64 + lane]);
        float2 acc;
        acc.x = fmaf(self.x, d * d, bb.x);
        acc.y = fmaf(self.y, d * d, bb.y);
        int e = rowptr[node];
        const int e1 = rowptr[node + 1];
        for (; e + 2 <= e1; e += 2) {
            int2 p0 = ep[e], p1 = ep[e + 1];
            float2 v0 = __half22float2(xw2[(size_t)p0.x * 64 + lane]);
            float2 v1 = __half22float2(xw2[(size_t)p1.x * 64 + lane]);
            float c0 = __int_as_float(p0.y), c1 = __int_as_float(p1.y);
            acc.x = fmaf(v0.x, c0, acc.x);
            acc.y = fmaf(v0.y, c0, acc.y);
            acc.x = fmaf(v1.x, c1, acc.x);
            acc.y = fmaf(v1.y, c1, acc.y);
        }
        if (e < e1) {
            int2 p0 = ep[e];
            float2 v0 = __half22float2(xw2[(size_t)p0.x * 64 + lane]);
            float c0 = __int_as_float(p0.y);
            acc.x = fmaf(v0.x, c0, acc.x);
            acc.y = fmaf(v0.y, c0, acc.y);
        }
        ((__half2*)out)[(size_t)node * 64 + lane] = __floats2half2_rn(acc.x, acc.y);
        s.x += acc.x; s.y += acc.y;
        q.x += acc.x * acc.x; q.y += acc.y * acc.y;
    }

    red[wv][lane] = make_float4(s.x, s.y, q.x, q.y);
    __syncthreads();
    if (wv == 0) {
        float4 r0 = red[0][lane], r1 = red[1][lane], r2 = red[2][lane], r3 = red[3][lane];
        atomicAdd(&sums[2 * lane],      r0.x + r1.x + r2.x + r3.x);
        atomicAdd(&sums[2 * lane + 1],  r0.y + r1.y + r2.y + r3.y);
        atomicAdd(&sumsq[2 * lane],     r0.z + r1.z + r2.z + r3.z);
        atomicAdd(&sumsq[2 * lane + 1], r0.w + r1.w + r2.w + r3.w);
    }
}

__global__ void bn_finalize(const float* __restrict__ sums, const float* __restrict__ sumsq,
                            const float* __restrict__ g, const float* __restrict__ be,
                            float* __restrict__ scale, float* __restrict__ shift, int n) {
    int c = threadIdx.x;
    float m = sums[c] / (float)n;
    float v = sumsq[c] / (float)n - m * m;
    float sc = g[c] * rsqrtf(fmaxf(v, 0.f) + EPS_BN);
    scale[c] = sc;
    shift[c] = be[c] - m * sc;
}

// ---------------- MLP head, tiled GEMM (fp16 input, BN2+ReLU fused) ---------
__global__ __launch_bounds__(256) void mlp_gemm(const f16* __restrict__ h,
                                                const float* __restrict__ scale,
                                                const float* __restrict__ shift,
                                                const float* __restrict__ Wm1,
                                                const float* __restrict__ bm1,
                                                const float* __restrict__ Wm2,
                                                const float* __restrict__ bm2,
                                                float* __restrict__ out, int n) {
    __shared__ float hs[64][HC + 4];
    __shared__ float red[64][17];
    const int tid  = threadIdx.x;
    const int row0 = blockIdx.x * 64;

    for (int i = tid; i < 1024; i += 256) {
        int r = i >> 4, g = i & 15;
        float4 lo = make_float4(0.f, 0.f, 0.f, 0.f);
        float4 hi = make_float4(0.f, 0.f, 0.f, 0.f);
        if (row0 + r < n) {
            f16x8 v = *(const f16x8*)(h + (size_t)(row0 + r) * HC + g * 8);
            float4 sa = *(const float4*)(scale + g * 8);
            float4 sb = *(const float4*)(scale + g * 8 + 4);
            float4 ha = *(const float4*)(shift + g * 8);
            float4 hb = *(const float4*)(shift + g * 8 + 4);
            lo.x = fmaxf(fmaf((float)v[0], sa.x, ha.x), 0.f);
            lo.y = fmaxf(fmaf((float)v[1], sa.y, ha.y), 0.f);
            lo.z = fmaxf(fmaf((float)v[2], sa.z, ha.z), 0.f);
            lo.w = fmaxf(fmaf((float)v[3], sa.w, ha.w), 0.f);
            hi.x = fmaxf(fmaf((float)v[4], sb.x, hb.x), 0.f);
            hi.y = fmaxf(fmaf((float)v[5], sb.y, hb.y), 0.f);
            hi.z = fmaxf(fmaf((float)v[6], sb.z, hb.z), 0.f);
            hi.w = fmaxf(fmaf((float)v[7], sb.w, hb.w), 0.f);
        }
        *(float4*)&hs[r][g * 8]     = lo;
        *(float4*)&hs[r][g * 8 + 4] = hi;
    }
    __syncthreads();

    const int cg = tid & 15;
    const int rg = tid >> 4;
    const int c0 = cg * 4;
    const int r0 = rg * 4;

    float acc[4][4];
#pragma unroll
    for (int i = 0; i < 4; ++i)
#pragma unroll
        for (int j = 0; j < 4; ++j) acc[i][j] = 0.f;

    for (int kk = 0; kk < HC; kk += 4) {
        float xv[4][4];
        *(float4*)xv[0] = *(const float4*)&hs[r0 + 0][kk];
        *(float4*)xv[1] = *(const float4*)&hs[r0 + 1][kk];
        *(float4*)xv[2] = *(const float4*)&hs[r0 + 2][kk];
        *(float4*)xv[3] = *(const float4*)&hs[r0 + 3][kk];
#pragma unroll
        for (int j = 0; j < 4; ++j) {
            float wv[4];
            *(float4*)wv = *(const float4*)(Wm1 + (size_t)(kk + j) * 64 + c0);
#pragma unroll
            for (int i = 0; i < 4; ++i)
#pragma unroll
                for (int c = 0; c < 4; ++c)
                    acc[i][c] = fmaf(xv[i][j], wv[c], acc[i][c]);
        }
    }

    float4 b1v = *(const float4*)(bm1 + c0);
    float4 w2v = *(const float4*)(Wm2 + c0);
#pragma unroll
    for (int i = 0; i < 4; ++i) {
        float t0 = fmaxf(acc[i][0] + b1v.x, 0.f) * w2v.x;
        float t1 = fmaxf(acc[i][1] + b1v.y, 0.f) * w2v.y;
        float t2 = fmaxf(acc[i][2] + b1v.z, 0.f) * w2v.z;
        float t3 = fmaxf(acc[i][3] + b1v.w, 0.f) * w2v.w;
        red[r0 + i][cg] = (t0 + t1) + (t2 + t3);
    }
    __syncthreads();

    if (tid < 64 && row0 + tid < n) {
        float s = 0.f;
#pragma unroll
        for (int g = 0; g < 16; ++g) s += red[tid][g];
        out[row0 + tid] = s + bm2[0];
    }
}

extern "C" void kernel_launch(void* const* d_in, const int* in_sizes, int n_in,
                              void* d_out, int out_size, void* d_ws, size_t ws_size,
                              hipStream_t stream) {
    const float* x   = (const float*)d_in[0];
    const int*   ei  = (const int*)  d_in[1];
    const float* W1  = (const float*)d_in[2];
    const float* b1  = (const float*)d_in[3];
    const float* g1  = (const float*)d_in[4];
    const float* be1 = (const float*)d_in[5];
    const float* W2  = (const float*)d_in[6];
    const float* b2  = (const float*)d_in[7];
    const float* g2  = (const float*)d_in[8];
    const float* be2 = (const float*)d_in[9];
    const float* Wm1 = (const float*)d_in[10];
    const float* bm1 = (const float*)d_in[11];
    const float* Wm2 = (const float*)d_in[12];
    const float* bm2 = (const float*)d_in[13];
    float* out = (float*)d_out;

    const int n = in_sizes[0] / HC;       // 100000
    const int E = in_sizes[1] / 2;        // 1600000
    const int* srcp = ei;
    const int* dstp = ei + E;

    char* ws = (char*)d_ws;
    size_t off = 0;
    auto alloc = [&](size_t bytes) { void* p = ws + off; off = (off + bytes + 511) & ~511ULL; return p; };
    float*  dis    = (float*) alloc((size_t)n * 4);
    int*    degi   = (int*)   alloc((size_t)n * 4);
    int*    cursor = (int*)   alloc((size_t)n * 4);
    int*    rowptr = (int*)   alloc((size_t)(n + 1) * 4);
    int*    bsums  = (int*)   alloc(4096);
    int2*   ep     = (int2*)  alloc((size_t)E * 8);
    f16*    xwh    = (f16*)   alloc((size_t)n * HC * 2);
    f16*    bufBh  = (f16*)   alloc((size_t)n * HC * 2);
    f16*    Wt1    = (f16*)   alloc((size_t)HC * HC * 2);
    f16*    Wt2    = (f16*)   alloc((size_t)HC * HC * 2);
    float*  sums   = (float*) alloc(1024);
    float*  sumsq  = sums + 128;
    float*  scale1 = (float*) alloc(1024);
    float*  shift1 = scale1 + 128;
    float*  scale2 = (float*) alloc(1024);
    float*  shift2 = scale2 + 128;

    const int gemmBlocks  = (n + 63) / 64;
    const int nScanBlocks = (n + 1023) / 1024;
    const int aggBlocks   = 1024;
    const int aggWaves    = aggBlocks * 4;

    // ---- CSR build (shared by both layers) ----
    hipMemsetAsync(degi, 0, (size_t)n * 4, stream);
    degi_kernel<<<(E + 255) / 256, 256, 0, stream>>>(dstp, degi, E);
    dis_kernel<<<(n + 255) / 256, 256, 0, stream>>>(degi, dis, n);
    scan1<<<nScanBlocks, 256, 0, stream>>>(degi, cursor, bsums, n);
    scan2<<<1, 64, 0, stream>>>(bsums, nScanBlocks);
    scan3<<<(n + 256) / 256, 256, 0, stream>>>(cursor, bsums, rowptr, n, E);
    edge_place<<<(E + 255) / 256, 256, 0, stream>>>(srcp, dstp, dis, cursor, ep, E);

    // ---- weight prep ----
    wprep<<<64, 256, 0, stream>>>(W1, Wt1);
    wprep<<<64, 256, 0, stream>>>(W2, Wt2);

    // ---- layer 1 ----
    gemm_mfma<0, 0><<<gemmBlocks, 256, 0, stream>>>(x, Wt1, nullptr, nullptr, xwh, n);
    hipMemsetAsync(sums, 0, 1024, stream);
    gcn_agg_f16<<<aggBlocks, 256, 0, stream>>>((const __half*)xwh, ep, rowptr, dis, b1,
                                               (__half*)bufBh, sums, sumsq, n, aggWaves);
    bn_finalize<<<1, 128, 0, stream>>>(sums, sumsq, g1, be1, scale1, shift1, n);

    // ---- layer 2 (BN1+ReLU fused into GEMM staging) ----
    gemm_mfma<1, 1><<<gemmBlocks, 256, 0, stream>>>(bufBh, Wt2, scale1, shift1, xwh, n);
    hipMemsetAsync(sums, 0, 1024, stream);
    gcn_agg_f16<<<aggBlocks, 256, 0, stream>>>((const __half*)xwh, ep, rowptr, dis, b2,
                                               (__half*)bufBh, sums, sumsq, n, aggWaves);
    bn_finalize<<<1, 128, 0, stream>>>(sums, sumsq, g2, be2, scale2, shift2, n);

    // ---- MLP head (BN2+ReLU fused) ----
    mlp_gemm<<<gemmBlocks, 256, 0, stream>>>(bufBh, scale2, shift2, Wm1, bm1, Wm2, bm2, out, n);
}

// Round 6
// 546.426 us; speedup vs baseline: 4.2978x; 1.2905x over previous
//
#include <hip/hip_runtime.h>
#include <hip/hip_fp16.h>

#define HC 128
#define EPS_BN 1e-5f
#define NSTRIPE 8
#define AGG_BLOCKS 3072

typedef _Float16 f16;
typedef f16  f16x8 __attribute__((ext_vector_type(8)));
typedef float f32x4 __attribute__((ext_vector_type(4)));

// ---------------- degree count (int) ----------------
__global__ void degi_kernel(const int* __restrict__ dst, int* __restrict__ degi, int E) {
    int e = blockIdx.x * 256 + threadIdx.x;
    if (e < E) atomicAdd(&degi[dst[e]], 1);
}

__global__ void dis_kernel(const int* __restrict__ degi, float* __restrict__ dis, int n) {
    int i = blockIdx.x * 256 + threadIdx.x;
    if (i < n) dis[i] = rsqrtf((float)degi[i] + 1.0f);  // +1 self-loop
}

// ---------------- exclusive scan of degi -> rowptr ----------------
__global__ __launch_bounds__(256) void scan1(const int* __restrict__ degi, int* __restrict__ excl,
                                             int* __restrict__ bsums, int n) {
    __shared__ int ts[256];
    const int tid = threadIdx.x;
    const int base = blockIdx.x * 1024 + tid * 4;
    int v0 = 0, v1 = 0, v2 = 0, v3 = 0;
    if (base + 3 < n) {
        int4 v = *(const int4*)(degi + base);
        v0 = v.x; v1 = v.y; v2 = v.z; v3 = v.w;
    } else {
        if (base + 0 < n) v0 = degi[base + 0];
        if (base + 1 < n) v1 = degi[base + 1];
        if (base + 2 < n) v2 = degi[base + 2];
        if (base + 3 < n) v3 = degi[base + 3];
    }
    int p1 = v0, p2 = v0 + v1, p3 = v0 + v1 + v2, total = p3 + v3;
    ts[tid] = total;
    __syncthreads();
    for (int off = 1; off < 256; off <<= 1) {
        int t = (tid >= off) ? ts[tid - off] : 0;
        __syncthreads();
        ts[tid] += t;
        __syncthreads();
    }
    int eb = (tid ? ts[tid - 1] : 0);
    if (tid == 255) bsums[blockIdx.x] = ts[255];
    if (base + 0 < n) excl[base + 0] = eb;
    if (base + 1 < n) excl[base + 1] = eb + p1;
    if (base + 2 < n) excl[base + 2] = eb + p2;
    if (base + 3 < n) excl[base + 3] = eb + p3;
}

__global__ void scan2(int* __restrict__ bsums, int nb) {
    if (threadIdx.x == 0) {
        int s = 0;
        for (int i = 0; i < nb; ++i) { int t = bsums[i]; bsums[i] = s; s += t; }
    }
}

__global__ void scan3(int* __restrict__ cursor, const int* __restrict__ bsums,
                      int* __restrict__ rowptr, int n, int E) {
    int i = blockIdx.x * 256 + threadIdx.x;
    if (i < n) {
        int v = cursor[i] + bsums[i >> 10];
        rowptr[i] = v;
        cursor[i] = v;
    }
    if (i == n) rowptr[n] = E;
}

// ---------------- edge placement into CSR (src index only, 4 B) -------------
__global__ void edge_place(const int* __restrict__ src, const int* __restrict__ dst,
                           int* __restrict__ cursor, int* __restrict__ srcs, int E) {
    int e = blockIdx.x * 256 + threadIdx.x;
    if (e < E) {
        int pos = atomicAdd(&cursor[dst[e]], 1);
        srcs[pos] = src[e];
    }
}

// ---------------- W transpose + fp16 convert: Wt[c][k] = W[k][c] ------------
__global__ void wprep(const float* __restrict__ W, f16* __restrict__ Wt) {
    int idx = blockIdx.x * 256 + threadIdx.x;   // 16384 total
    if (idx < HC * HC) {
        int k = idx >> 7, c = idx & 127;
        Wt[(size_t)c * HC + k] = (f16)W[idx];
    }
}

// ---------------- MFMA GEMM: Y[n,128](f16) = T(X)[n,128] @ W[128,128] -------
template<int SRC_F16, int TRANS>
__global__ __launch_bounds__(256) void gemm_mfma(const void* __restrict__ Xv,
                                                 const f16* __restrict__ Wt,
                                                 const float* __restrict__ scale,
                                                 const float* __restrict__ shift,
                                                 f16* __restrict__ Y, int n) {
    __shared__ f16 Ah[64][136];
    __shared__ f16 Bh[128][136];
    const int tid  = threadIdx.x;
    const int row0 = blockIdx.x * 64;

#pragma unroll
    for (int i = 0; i < 8; ++i) {
        int idx = i * 256 + tid;
        int r = idx >> 4, g = idx & 15;
        *(f16x8*)&Bh[r][g * 8] = *(const f16x8*)(Wt + (size_t)r * HC + g * 8);
    }
#pragma unroll
    for (int i = 0; i < 4; ++i) {
        int idx = i * 256 + tid;
        int r = idx >> 4, g = idx & 15;
        int grow = row0 + r;
        f16x8 h = {};
        if (grow < n) {
            if constexpr (SRC_F16) {
                f16x8 v = *(const f16x8*)((const f16*)Xv + (size_t)grow * HC + g * 8);
                if constexpr (TRANS) {
#pragma unroll
                    for (int j = 0; j < 8; ++j) {
                        float f = (float)v[j];
                        f = fmaxf(fmaf(f, scale[g * 8 + j], shift[g * 8 + j]), 0.f);
                        h[j] = (f16)f;
                    }
                } else h = v;
            } else {
                const float* X = (const float*)Xv;
                float4 a = *(const float4*)(X + (size_t)grow * HC + g * 8);
                float4 c = *(const float4*)(X + (size_t)grow * HC + g * 8 + 4);
                h[0] = (f16)a.x; h[1] = (f16)a.y; h[2] = (f16)a.z; h[3] = (f16)a.w;
                h[4] = (f16)c.x; h[5] = (f16)c.y; h[6] = (f16)c.z; h[7] = (f16)c.w;
            }
        }
        *(f16x8*)&Ah[r][g * 8] = h;
    }
    __syncthreads();

    const int wv   = tid >> 6;
    const int lane = tid & 63;
    const int m    = lane & 15;
    const int kq   = (lane >> 4) * 8;

    f32x4 acc[8] = {};
#pragma unroll
    for (int kc = 0; kc < HC; kc += 32) {
        f16x8 a = *(const f16x8*)&Ah[wv * 16 + m][kc + kq];
#pragma unroll
        for (int t = 0; t < 8; ++t) {
            f16x8 b = *(const f16x8*)&Bh[t * 16 + m][kc + kq];
            acc[t] = __builtin_amdgcn_mfma_f32_16x16x32_f16(a, b, acc[t], 0, 0, 0);
        }
    }

    const int rbase = row0 + wv * 16 + (lane >> 4) * 4;
#pragma unroll
    for (int t = 0; t < 8; ++t) {
#pragma unroll
        for (int r = 0; r < 4; ++r) {
            int grow = rbase + r;
            if (grow < n)
                Y[(size_t)grow * HC + t * 16 + m] = (f16)acc[t][r];
        }
    }
}

// ---------------- CSR gather agg: 4 edges/wave-iter, 16B/lane ---------------
// out[v] = dis[v]*(sum_e dis[s]*xw[s] + dis[v]*xw[v]) + b ; fused BN stats.
__global__ __launch_bounds__(256) void gcn_agg_f16(const f16* __restrict__ xw,
                                                   const int* __restrict__ srcs,
                                                   const int* __restrict__ rowptr,
                                                   const float* __restrict__ dis,
                                                   const float* __restrict__ bias,
                                                   f16* __restrict__ out,
                                                   float* __restrict__ stats,
                                                   int n, int nwaves) {
    __shared__ float lds_s[4][128], lds_q[4][128];
    const int wv   = threadIdx.x >> 6;
    const int lane = threadIdx.x & 63;
    const int g    = lane >> 4;      // edge subgroup 0..3
    const int cg   = lane & 15;      // channel group (8 channels)

    float b8[8];
#pragma unroll
    for (int j = 0; j < 8; ++j) b8[j] = bias[cg * 8 + j];

    float s8[8] = {}, q8[8] = {};

    for (int node = blockIdx.x * 4 + wv; node < n; node += nwaves) {
        const int e0 = rowptr[node];
        const int e1 = rowptr[node + 1];
        float acc[8] = {};
        for (int e = e0; e < e1; e += 4) {
            int idx = e + g;
            bool valid = idx < e1;
            int sidx = srcs[valid ? idx : e0];
            float w = valid ? dis[sidx] : 0.f;
            f16x8 v = *(const f16x8*)(xw + (size_t)sidx * HC + cg * 8);
#pragma unroll
            for (int j = 0; j < 8; ++j)
                acc[j] = fmaf((float)v[j], w, acc[j]);
        }
        // reduce across the 4 edge subgroups (lane^16, lane^32)
#pragma unroll
        for (int j = 0; j < 8; ++j) acc[j] += __shfl_xor(acc[j], 16);
#pragma unroll
        for (int j = 0; j < 8; ++j) acc[j] += __shfl_xor(acc[j], 32);

        if (g == 0) {
            float dv = dis[node];
            f16x8 self = *(const f16x8*)(xw + (size_t)node * HC + cg * 8);
            f16x8 o;
#pragma unroll
            for (int j = 0; j < 8; ++j) {
                float r = fmaf(acc[j] + (float)self[j] * dv, dv, b8[j]);
                o[j] = (f16)r;
                s8[j] += r;
                q8[j] += r * r;
            }
            *(f16x8*)(out + (size_t)node * HC + cg * 8) = o;
        }
    }

    if (g == 0) {
#pragma unroll
        for (int j = 0; j < 8; ++j) {
            lds_s[wv][cg * 8 + j] = s8[j];
            lds_q[wv][cg * 8 + j] = q8[j];
        }
    }
    __syncthreads();
    float* stripe = stats + (size_t)(blockIdx.x & (NSTRIPE - 1)) * 256;
    if (threadIdx.x < 128) {
        float s = lds_s[0][threadIdx.x] + lds_s[1][threadIdx.x] +
                  lds_s[2][threadIdx.x] + lds_s[3][threadIdx.x];
        float q = lds_q[0][threadIdx.x] + lds_q[1][threadIdx.x] +
                  lds_q[2][threadIdx.x] + lds_q[3][threadIdx.x];
        atomicAdd(&stripe[threadIdx.x], s);
        atomicAdd(&stripe[128 + threadIdx.x], q);
    }
}

__global__ void bn_finalize(const float* __restrict__ stats,
                            const float* __restrict__ g, const float* __restrict__ be,
                            float* __restrict__ scale, float* __restrict__ shift, int n) {
    int c = threadIdx.x;
    float s = 0.f, q = 0.f;
    for (int t = 0; t < NSTRIPE; ++t) {
        s += stats[t * 256 + c];
        q += stats[t * 256 + 128 + c];
    }
    float m = s / (float)n;
    float v = q / (float)n - m * m;
    float sc = g[c] * rsqrtf(fmaxf(v, 0.f) + EPS_BN);
    scale[c] = sc;
    shift[c] = be[c] - m * sc;
}

// ---------------- MLP head, tiled GEMM (fp16 input, BN2+ReLU fused) ---------
__global__ __launch_bounds__(256) void mlp_gemm(const f16* __restrict__ h,
                                                const float* __restrict__ scale,
                                                const float* __restrict__ shift,
                                                const float* __restrict__ Wm1,
                                                const float* __restrict__ bm1,
                                                const float* __restrict__ Wm2,
                                                const float* __restrict__ bm2,
                                                float* __restrict__ out, int n) {
    __shared__ float hs[64][HC + 4];
    __shared__ float red[64][17];
    const int tid  = threadIdx.x;
    const int row0 = blockIdx.x * 64;

    for (int i = tid; i < 1024; i += 256) {
        int r = i >> 4, g = i & 15;
        float4 lo = make_float4(0.f, 0.f, 0.f, 0.f);
        float4 hi = make_float4(0.f, 0.f, 0.f, 0.f);
        if (row0 + r < n) {
            f16x8 v = *(const f16x8*)(h + (size_t)(row0 + r) * HC + g * 8);
            float4 sa = *(const float4*)(scale + g * 8);
            float4 sb = *(const float4*)(scale + g * 8 + 4);
            float4 ha = *(const float4*)(shift + g * 8);
            float4 hb = *(const float4*)(shift + g * 8 + 4);
            lo.x = fmaxf(fmaf((float)v[0], sa.x, ha.x), 0.f);
            lo.y = fmaxf(fmaf((float)v[1], sa.y, ha.y), 0.f);
            lo.z = fmaxf(fmaf((float)v[2], sa.z, ha.z), 0.f);
            lo.w = fmaxf(fmaf((float)v[3], sa.w, ha.w), 0.f);
            hi.x = fmaxf(fmaf((float)v[4], sb.x, hb.x), 0.f);
            hi.y = fmaxf(fmaf((float)v[5], sb.y, hb.y), 0.f);
            hi.z = fmaxf(fmaf((float)v[6], sb.z, hb.z), 0.f);
            hi.w = fmaxf(fmaf((float)v[7], sb.w, hb.w), 0.f);
        }
        *(float4*)&hs[r][g * 8]     = lo;
        *(float4*)&hs[r][g * 8 + 4] = hi;
    }
    __syncthreads();

    const int cg = tid & 15;
    const int rg = tid >> 4;
    const int c0 = cg * 4;
    const int r0 = rg * 4;

    float acc[4][4];
#pragma unroll
    for (int i = 0; i < 4; ++i)
#pragma unroll
        for (int j = 0; j < 4; ++j) acc[i][j] = 0.f;

    for (int kk = 0; kk < HC; kk += 4) {
        float xv[4][4];
        *(float4*)xv[0] = *(const float4*)&hs[r0 + 0][kk];
        *(float4*)xv[1] = *(const float4*)&hs[r0 + 1][kk];
        *(float4*)xv[2] = *(const float4*)&hs[r0 + 2][kk];
        *(float4*)xv[3] = *(const float4*)&hs[r0 + 3][kk];
#pragma unroll
        for (int j = 0; j < 4; ++j) {
            float wv[4];
            *(float4*)wv = *(const float4*)(Wm1 + (size_t)(kk + j) * 64 + c0);
#pragma unroll
            for (int i = 0; i < 4; ++i)
#pragma unroll
                for (int c = 0; c < 4; ++c)
                    acc[i][c] = fmaf(xv[i][j], wv[c], acc[i][c]);
        }
    }

    float4 b1v = *(const float4*)(bm1 + c0);
    float4 w2v = *(const float4*)(Wm2 + c0);
#pragma unroll
    for (int i = 0; i < 4; ++i) {
        float t0 = fmaxf(acc[i][0] + b1v.x, 0.f) * w2v.x;
        float t1 = fmaxf(acc[i][1] + b1v.y, 0.f) * w2v.y;
        float t2 = fmaxf(acc[i][2] + b1v.z, 0.f) * w2v.z;
        float t3 = fmaxf(acc[i][3] + b1v.w, 0.f) * w2v.w;
        red[r0 + i][cg] = (t0 + t1) + (t2 + t3);
    }
    __syncthreads();

    if (tid < 64 && row0 + tid < n) {
        float s = 0.f;
#pragma unroll
        for (int g = 0; g < 16; ++g) s += red[tid][g];
        out[row0 + tid] = s + bm2[0];
    }
}

extern "C" void kernel_launch(void* const* d_in, const int* in_sizes, int n_in,
                              void* d_out, int out_size, void* d_ws, size_t ws_size,
                              hipStream_t stream) {
    const float* x   = (const float*)d_in[0];
    const int*   ei  = (const int*)  d_in[1];
    const float* W1  = (const float*)d_in[2];
    const float* b1  = (const float*)d_in[3];
    const float* g1  = (const float*)d_in[4];
    const float* be1 = (const float*)d_in[5];
    const float* W2  = (const float*)d_in[6];
    const float* b2  = (const float*)d_in[7];
    const float* g2  = (const float*)d_in[8];
    const float* be2 = (const float*)d_in[9];
    const float* Wm1 = (const float*)d_in[10];
    const float* bm1 = (const float*)d_in[11];
    const float* Wm2 = (const float*)d_in[12];
    const float* bm2 = (const float*)d_in[13];
    float* out = (float*)d_out;

    const int n = in_sizes[0] / HC;       // 100000
    const int E = in_sizes[1] / 2;        // 1600000
    const int* srcp = ei;
    const int* dstp = ei + E;

    char* ws = (char*)d_ws;
    size_t off = 0;
    auto alloc = [&](size_t bytes) { void* p = ws + off; off = (off + bytes + 511) & ~511ULL; return p; };
    float*  dis    = (float*) alloc((size_t)n * 4);
    int*    degi   = (int*)   alloc((size_t)n * 4);
    int*    cursor = (int*)   alloc((size_t)n * 4);
    int*    rowptr = (int*)   alloc((size_t)(n + 1) * 4);
    int*    bsums  = (int*)   alloc(4096);
    int*    srcs   = (int*)   alloc((size_t)E * 4);
    f16*    xwh    = (f16*)   alloc((size_t)n * HC * 2);
    f16*    bufBh  = (f16*)   alloc((size_t)n * HC * 2);
    f16*    Wt1    = (f16*)   alloc((size_t)HC * HC * 2);
    f16*    Wt2    = (f16*)   alloc((size_t)HC * HC * 2);
    float*  stats  = (float*) alloc(NSTRIPE * 256 * 4);
    float*  scale1 = (float*) alloc(1024);
    float*  shift1 = scale1 + 128;
    float*  scale2 = (float*) alloc(1024);
    float*  shift2 = scale2 + 128;

    const int gemmBlocks  = (n + 63) / 64;
    const int nScanBlocks = (n + 1023) / 1024;
    const int aggWaves    = AGG_BLOCKS * 4;

    // ---- CSR build (shared by both layers) ----
    hipMemsetAsync(degi, 0, (size_t)n * 4, stream);
    degi_kernel<<<(E + 255) / 256, 256, 0, stream>>>(dstp, degi, E);
    dis_kernel<<<(n + 255) / 256, 256, 0, stream>>>(degi, dis, n);
    scan1<<<nScanBlocks, 256, 0, stream>>>(degi, cursor, bsums, n);
    scan2<<<1, 64, 0, stream>>>(bsums, nScanBlocks);
    scan3<<<(n + 256) / 256, 256, 0, stream>>>(cursor, bsums, rowptr, n, E);
    edge_place<<<(E + 255) / 256, 256, 0, stream>>>(srcp, dstp, cursor, srcs, E);

    // ---- weight prep ----
    wprep<<<64, 256, 0, stream>>>(W1, Wt1);
    wprep<<<64, 256, 0, stream>>>(W2, Wt2);

    // ---- layer 1 ----
    gemm_mfma<0, 0><<<gemmBlocks, 256, 0, stream>>>(x, Wt1, nullptr, nullptr, xwh, n);
    hipMemsetAsync(stats, 0, NSTRIPE * 256 * 4, stream);
    gcn_agg_f16<<<AGG_BLOCKS, 256, 0, stream>>>(xwh, srcs, rowptr, dis, b1,
                                                bufBh, stats, n, aggWaves);
    bn_finalize<<<1, 128, 0, stream>>>(stats, g1, be1, scale1, shift1, n);

    // ---- layer 2 (BN1+ReLU fused into GEMM staging) ----
    gemm_mfma<1, 1><<<gemmBlocks, 256, 0, stream>>>(bufBh, Wt2, scale1, shift1, xwh, n);
    hipMemsetAsync(stats, 0, NSTRIPE * 256 * 4, stream);
    gcn_agg_f16<<<AGG_BLOCKS, 256, 0, stream>>>(xwh, srcs, rowptr, dis, b2,
                                                bufBh, stats, n, aggWaves);
    bn_finalize<<<1, 128, 0, stream>>>(stats, g2, be2, scale2, shift2, n);

    // ---- MLP head (BN2+ReLU fused) ----
    mlp_gemm<<<gemmBlocks, 256, 0, stream>>>(bufBh, scale2, shift2, Wm1, bm1, Wm2, bm2, out, n);
}